// Round 1
// baseline (244.753 us; speedup 1.0000x reference)
//
#include <hip/hip_runtime.h>
#include <hip/hip_bf16.h>
#include <stdint.h>

typedef short s16x8 __attribute__((ext_vector_type(8)));
typedef float f32x4 __attribute__((ext_vector_type(4)));

#define BSZ 2
#define SQL 2048
#define DMODEL 1024
#define NHEAD 16
#define DKH 64

// fp32 -> bf16 round-to-nearest-even (inputs are normal; NaN path not needed)
__device__ __forceinline__ ushort f2bf(float f) {
  uint32_t u = __float_as_uint(f);
  u += 0x7fffu + ((u >> 16) & 1u);
  return (ushort)(u >> 16);
}

// async global->LDS, 16B per lane. LDS dest must be wave-uniform base; HW adds lane*16.
__device__ __forceinline__ void gload_lds16(const ushort* g, ushort* l) {
  __builtin_amdgcn_global_load_lds((const __attribute__((address_space(1))) void*)g,
                                   (__attribute__((address_space(3))) void*)l,
                                   16, 0, 0);
}

// ---------------- fp32 -> bf16 conversion passes ----------------
__global__ void cvt3(const float* __restrict__ s0, const float* __restrict__ s1,
                     const float* __restrict__ s2, ushort* __restrict__ d0,
                     ushort* __restrict__ d1, ushort* __restrict__ d2) {
  const float* s = (blockIdx.y == 0) ? s0 : (blockIdx.y == 1) ? s1 : s2;
  ushort* d = (blockIdx.y == 0) ? d0 : (blockIdx.y == 1) ? d1 : d2;
  int i = (blockIdx.x * 256 + threadIdx.x) * 4;
  float4 v = *(const float4*)(s + i);
  ushort4 o;
  o.x = f2bf(v.x); o.y = f2bf(v.y); o.z = f2bf(v.z); o.w = f2bf(v.w);
  *(ushort4*)(d + i) = o;
}

__global__ void cvt4(const float* __restrict__ s0, const float* __restrict__ s1,
                     const float* __restrict__ s2, const float* __restrict__ s3,
                     ushort* __restrict__ d0, ushort* __restrict__ d1,
                     ushort* __restrict__ d2, ushort* __restrict__ d3) {
  const float* s = (blockIdx.y == 0) ? s0 : (blockIdx.y == 1) ? s1 : (blockIdx.y == 2) ? s2 : s3;
  ushort* d = (blockIdx.y == 0) ? d0 : (blockIdx.y == 1) ? d1 : (blockIdx.y == 2) ? d2 : d3;
  int i = (blockIdx.x * 256 + threadIdx.x) * 4;
  float4 v = *(const float4*)(s + i);
  ushort4 o;
  o.x = f2bf(v.x); o.y = f2bf(v.y); o.z = f2bf(v.z); o.w = f2bf(v.w);
  *(ushort4*)(d + i) = o;
}

// ---------------- GEMM: C[M,N] = A[M,K] * B[N,K]^T  (x @ W.T), bf16 in, fp32 acc ---------
// M=4096 N=1024 K=1024 fixed. 128x128 tile, BK=32, 4 waves (2x2 of 64x64), 16x16x32 MFMA.
// mode 0/1: bf16 out, head-major Qh/Kh layout [b][h][s][dk]
// mode 2  : bf16 out, transposed  Vt layout   [b][h][dk][s]
// mode 3  : fp32 out, row-major [M][N] (final output)
__global__ __launch_bounds__(256) void gemm_bt(const ushort* __restrict__ A,
                                               const ushort* __restrict__ B,
                                               void* __restrict__ D_, float scale, int mode) {
  constexpr int KDIM = 1024;
  __shared__ __align__(16) ushort sA[128 * 32];
  __shared__ __align__(16) ushort sB[128 * 32];
  const int t = threadIdx.x;
  const int w = t >> 6, lane = t & 63;
  const int m0 = blockIdx.x * 128, n0 = blockIdx.y * 128;
  const int wm = (w >> 1) * 64, wn = (w & 1) * 64;
  const int lrow = lane & 15, lk = (lane >> 4) * 8;
  f32x4 acc[4][4] = {};

  for (int kt = 0; kt < KDIM / 32; ++kt) {
#pragma unroll
    for (int i = 0; i < 2; ++i) {
      int ci = i * 256 + t;          // 512 chunks of 16B per 8KB tile
      int row = ci >> 2;             // 4 chunks per 64B row
      int ce = (ci & 3) * 8;         // element offset in row
      gload_lds16(A + (size_t)(m0 + row) * KDIM + kt * 32 + ce, sA + (i * 256 + w * 64) * 8);
      gload_lds16(B + (size_t)(n0 + row) * KDIM + kt * 32 + ce, sB + (i * 256 + w * 64) * 8);
    }
    asm volatile("s_waitcnt vmcnt(0)" ::: "memory");
    __syncthreads();
    s16x8 af[4], bfr[4];
#pragma unroll
    for (int mi = 0; mi < 4; ++mi)
      af[mi] = *(const s16x8*)(sA + (wm + mi * 16 + lrow) * 32 + lk);
#pragma unroll
    for (int ni = 0; ni < 4; ++ni)
      bfr[ni] = *(const s16x8*)(sB + (wn + ni * 16 + lrow) * 32 + lk);
#pragma unroll
    for (int mi = 0; mi < 4; ++mi)
#pragma unroll
      for (int ni = 0; ni < 4; ++ni)
        acc[mi][ni] = __builtin_amdgcn_mfma_f32_16x16x32_bf16(af[mi], bfr[ni], acc[mi][ni], 0, 0, 0);
    __syncthreads();
  }

  // epilogue: C/D layout col=lane&15, row=(lane>>4)*4+reg
#pragma unroll
  for (int mi = 0; mi < 4; ++mi) {
#pragma unroll
    for (int ni = 0; ni < 4; ++ni) {
#pragma unroll
      for (int r = 0; r < 4; ++r) {
        int m = m0 + wm + mi * 16 + (lane >> 4) * 4 + r;
        int n = n0 + wn + ni * 16 + (lane & 15);
        float val = acc[mi][ni][r] * scale;
        if (mode == 3) {
          ((float*)D_)[(size_t)m * 1024 + n] = val;
        } else {
          int b = m >> 11, s = m & 2047, h = n >> 6, d = n & 63;
          ushort bv = f2bf(val);
          if (mode == 2)
            ((ushort*)D_)[((size_t)((b * 16 + h) * 64 + d)) * 2048 + s] = bv;  // V^T
          else
            ((ushort*)D_)[((size_t)((b * 16 + h) * 2048 + s)) * 64 + d] = bv;  // Qh/Kh
        }
      }
    }
  }
}

// ---------------- causal flash attention ----------------
// grid (SQ/64, B*H). 4 waves; each wave owns 16 q-rows. KV tiles of 64.
// Qh/Kh: [bh][s][64] bf16 (Q pre-scaled by 0.125). Vt: [bh][64][s] bf16.
// Z out: [b][s][h*64+d] bf16.
__global__ __launch_bounds__(256) void attn_fwd(const ushort* __restrict__ Qh,
                                                const ushort* __restrict__ Kh,
                                                const ushort* __restrict__ Vt,
                                                ushort* __restrict__ Z) {
  __shared__ __align__(16) ushort sK[64 * 64];     // [k][d], chunk-XOR swizzled
  __shared__ __align__(16) ushort sV[64 * 64];     // [d][k], chunk-XOR swizzled
  __shared__ __align__(16) ushort sP[4][16 * 72];  // per-wave P, row stride 144B
  const int t = threadIdx.x, w = t >> 6, lane = t & 63;
  const int qt = blockIdx.x, bh = blockIdx.y;
  const ushort* Qb = Qh + (size_t)bh * SQL * DKH;
  const ushort* Kb = Kh + (size_t)bh * SQL * DKH;
  const ushort* Vb = Vt + (size_t)bh * DKH * SQL;
  const int lcol = lane & 15, lhi = lane >> 4;
  const int qr0 = qt * 64 + w * 16;

  // Q A-fragments live in registers for the whole block
  s16x8 qf0, qf1;
  {
    const ushort* qp = Qb + (size_t)(qr0 + lcol) * DKH + lhi * 8;
    qf0 = *(const s16x8*)qp;
    qf1 = *(const s16x8*)(qp + 32);
  }
  float mr[4], lr[4];
  f32x4 o[4] = {};
#pragma unroll
  for (int r = 0; r < 4; ++r) { mr[r] = -1e30f; lr[r] = 0.f; }
  ushort* Pw = &sP[w][0];

  for (int kb = 0; kb <= qt; ++kb) {
    // stage K tile [64][64] and V^T tile [64][64]; source pre-swizzled: chunk ^= row&7
#pragma unroll
    for (int i = 0; i < 2; ++i) {
      int ci = i * 256 + t;
      int row = ci >> 3, cc = ci & 7;
      int sc = cc ^ (row & 7);
      gload_lds16(Kb + (size_t)(kb * 64 + row) * DKH + sc * 8, sK + (i * 256 + w * 64) * 8);
      gload_lds16(Vb + (size_t)row * SQL + kb * 64 + sc * 8, sV + (i * 256 + w * 64) * 8);
    }
    asm volatile("s_waitcnt vmcnt(0)" ::: "memory");
    __syncthreads();

    // QK^T: D[16q x 16k] per kt; B-frag = K[kcol][d0..d0+8] (contiguous, swizzled read)
    f32x4 sc4[4];
#pragma unroll
    for (int ktt = 0; ktt < 4; ++ktt) {
      int row = ktt * 16 + lcol;
      int c0 = lhi ^ (row & 7);
      int c1 = (lhi + 4) ^ (row & 7);
      s16x8 k0 = *(const s16x8*)(sK + row * 64 + c0 * 8);
      s16x8 k1 = *(const s16x8*)(sK + row * 64 + c1 * 8);
      f32x4 a = {};
      a = __builtin_amdgcn_mfma_f32_16x16x32_bf16(qf0, k0, a, 0, 0, 0);
      a = __builtin_amdgcn_mfma_f32_16x16x32_bf16(qf1, k1, a, 0, 0, 0);
      sc4[ktt] = a;
    }
    // causal mask: only diagonal tile needs it
    if (kb == qt) {
#pragma unroll
      for (int ktt = 0; ktt < 4; ++ktt) {
        int kloc = ktt * 16 + lcol;
#pragma unroll
        for (int r = 0; r < 4; ++r) {
          int qloc = w * 16 + lhi * 4 + r;
          if (kloc > qloc) sc4[ktt][r] = -1e30f;
        }
      }
    }
    // online softmax (rows live in (lane>>4)*4+r; cols spread over lane&15)
#pragma unroll
    for (int r = 0; r < 4; ++r) {
      float tm = fmaxf(fmaxf(sc4[0][r], sc4[1][r]), fmaxf(sc4[2][r], sc4[3][r]));
      tm = fmaxf(tm, __shfl_xor(tm, 1));
      tm = fmaxf(tm, __shfl_xor(tm, 2));
      tm = fmaxf(tm, __shfl_xor(tm, 4));
      tm = fmaxf(tm, __shfl_xor(tm, 8));
      float mn = fmaxf(mr[r], tm);
      float alpha = __expf(mr[r] - mn);
      float rs = 0.f;
#pragma unroll
      for (int ktt = 0; ktt < 4; ++ktt) {
        float p = __expf(sc4[ktt][r] - mn);
        sc4[ktt][r] = p;
        rs += p;
      }
      rs += __shfl_xor(rs, 1);
      rs += __shfl_xor(rs, 2);
      rs += __shfl_xor(rs, 4);
      rs += __shfl_xor(rs, 8);
      mr[r] = mn;
      lr[r] = lr[r] * alpha + rs;
      o[0][r] *= alpha; o[1][r] *= alpha; o[2][r] *= alpha; o[3][r] *= alpha;
    }
    // P: C-layout -> A-layout transpose via per-wave LDS (no barrier needed, same wave)
#pragma unroll
    for (int ktt = 0; ktt < 4; ++ktt)
#pragma unroll
      for (int r = 0; r < 4; ++r)
        Pw[(lhi * 4 + r) * 72 + ktt * 16 + lcol] = f2bf(sc4[ktt][r]);
    // PV: o[q][d] += P[q][k] * V[k][d]
#pragma unroll
    for (int kc = 0; kc < 2; ++kc) {
      s16x8 pf = *(const s16x8*)(Pw + lcol * 72 + kc * 32 + lhi * 8);
#pragma unroll
      for (int dt = 0; dt < 4; ++dt) {
        int row = dt * 16 + lcol;
        int cc = (lhi + 4 * kc) ^ (row & 7);
        s16x8 vf = *(const s16x8*)(sV + row * 64 + cc * 8);
        o[dt] = __builtin_amdgcn_mfma_f32_16x16x32_bf16(pf, vf, o[dt], 0, 0, 0);
      }
    }
    __syncthreads();
  }

  // epilogue: O /= l, write Z[b][s][h*64+d]
  const int b = bh >> 4, h = bh & 15;
#pragma unroll
  for (int r = 0; r < 4; ++r) {
    float inv = 1.0f / lr[r];
    int q = qr0 + lhi * 4 + r;
    size_t base = ((size_t)(b * SQL + q)) * DMODEL + h * DKH + lcol;
#pragma unroll
    for (int dt = 0; dt < 4; ++dt)
      Z[base + dt * 16] = f2bf(o[dt][r] * inv);
  }
}

// ---------------- launch ----------------
extern "C" void kernel_launch(void* const* d_in, const int* in_sizes, int n_in,
                              void* d_out, int out_size, void* d_ws, size_t ws_size,
                              hipStream_t stream) {
  const float* q = (const float*)d_in[0];
  const float* k = (const float*)d_in[1];
  const float* v = (const float*)d_in[2];
  // d_in[3] = causal mask (bool) -- derived from indices instead, ignored
  const float* wq = (const float*)d_in[4];
  const float* wk = (const float*)d_in[5];
  const float* wv = (const float*)d_in[6];
  const float* wo = (const float*)d_in[7];

  const size_t NBIG = (size_t)BSZ * SQL * DMODEL;   // 4194304
  const size_t NW = (size_t)DMODEL * DMODEL;        // 1048576
  ushort* qb = (ushort*)d_ws;
  ushort* kb = qb + NBIG;
  ushort* vb = kb + NBIG;
  ushort* wqb = vb + NBIG;
  ushort* wkb = wqb + NW;
  ushort* wvb = wkb + NW;
  ushort* wob = wvb + NW;
  ushort* Qh = wob + NW;
  ushort* Kh = Qh + NBIG;
  ushort* Vt = Kh + NBIG;
  ushort* Z  = Vt + NBIG;   // total 64 MiB of d_ws

  cvt3<<<dim3((unsigned)(NBIG / 1024), 3), 256, 0, stream>>>(q, k, v, qb, kb, vb);
  cvt4<<<dim3((unsigned)(NW / 1024), 4), 256, 0, stream>>>(wq, wk, wv, wo, wqb, wkb, wvb, wob);
  // projections (Q pre-scaled by 1/sqrt(dk) = 0.125)
  gemm_bt<<<dim3(32, 8), 256, 0, stream>>>(qb, wqb, Qh, 0.125f, 0);
  gemm_bt<<<dim3(32, 8), 256, 0, stream>>>(kb, wkb, Kh, 1.0f, 1);
  gemm_bt<<<dim3(32, 8), 256, 0, stream>>>(vb, wvb, Vt, 1.0f, 2);
  attn_fwd<<<dim3(SQL / 64, BSZ * NHEAD), 256, 0, stream>>>(Qh, Kh, Vt, Z);
  gemm_bt<<<dim3(32, 8), 256, 0, stream>>>(Z, wob, d_out, 1.0f, 3);
}

// Round 2
// 153.472 us; speedup vs baseline: 1.5948x; 1.5948x over previous
//
#include <hip/hip_runtime.h>
#include <hip/hip_bf16.h>
#include <stdint.h>

typedef short s16x8 __attribute__((ext_vector_type(8)));
typedef float f32x4 __attribute__((ext_vector_type(4)));

#define BSZ 2
#define SQL 2048
#define DMODEL 1024
#define NHEAD 16
#define DKH 64

// fp32 -> bf16 round-to-nearest-even
__device__ __forceinline__ ushort f2bf(float f) {
  uint32_t u = __float_as_uint(f);
  u += 0x7fffu + ((u >> 16) & 1u);
  return (ushort)(u >> 16);
}

// async global->LDS, 16B per lane. LDS dest is wave-uniform base + lane*16.
__device__ __forceinline__ void gload_lds16(const ushort* g, ushort* l) {
  __builtin_amdgcn_global_load_lds((const __attribute__((address_space(1))) void*)g,
                                   (__attribute__((address_space(3))) void*)l,
                                   16, 0, 0);
}

// ---------------- fp32 -> bf16 conversion passes ----------------
__global__ void cvt3(const float* __restrict__ s0, const float* __restrict__ s1,
                     const float* __restrict__ s2, ushort* __restrict__ d0,
                     ushort* __restrict__ d1, ushort* __restrict__ d2) {
  const float* s = (blockIdx.y == 0) ? s0 : (blockIdx.y == 1) ? s1 : s2;
  ushort* d = (blockIdx.y == 0) ? d0 : (blockIdx.y == 1) ? d1 : d2;
  int i = (blockIdx.x * 256 + threadIdx.x) * 4;
  float4 v = *(const float4*)(s + i);
  ushort4 o;
  o.x = f2bf(v.x); o.y = f2bf(v.y); o.z = f2bf(v.z); o.w = f2bf(v.w);
  *(ushort4*)(d + i) = o;
}

__global__ void cvt4(const float* __restrict__ s0, const float* __restrict__ s1,
                     const float* __restrict__ s2, const float* __restrict__ s3,
                     ushort* __restrict__ d0, ushort* __restrict__ d1,
                     ushort* __restrict__ d2, ushort* __restrict__ d3) {
  const float* s = (blockIdx.y == 0) ? s0 : (blockIdx.y == 1) ? s1 : (blockIdx.y == 2) ? s2 : s3;
  ushort* d = (blockIdx.y == 0) ? d0 : (blockIdx.y == 1) ? d1 : (blockIdx.y == 2) ? d2 : d3;
  int i = (blockIdx.x * 256 + threadIdx.x) * 4;
  float4 v = *(const float4*)(s + i);
  ushort4 o;
  o.x = f2bf(v.x); o.y = f2bf(v.y); o.z = f2bf(v.z); o.w = f2bf(v.w);
  *(ushort4*)(d + i) = o;
}

// ---------------- GEMM core: C[M,N] = A[M,K] * B[N,K]^T, bf16 in, fp32 acc -------------
// M=4096 N=1024 K=1024. 128x128 tile, BK=32, 4 waves (2x2 of 64x64), 16x16x32 MFMA.
// Double-buffered LDS, counted vmcnt(4), raw barriers (T3-min + T4 template).
__device__ __forceinline__ void gemm_core(const ushort* __restrict__ A,
                                          const ushort* __restrict__ B,
                                          ushort* sA, ushort* sB, f32x4 (&acc)[4][4]) {
  const int t = threadIdx.x, w = t >> 6, lane = t & 63;
  const int lrow = lane & 15, lk = (lane >> 4) * 8;
  const int m0 = blockIdx.x * 128, n0 = blockIdx.y * 128;
  const int wm = (w >> 1) * 64, wn = (w & 1) * 64;

  auto stage = [&](int kt, int buf) {
#pragma unroll
    for (int i = 0; i < 2; ++i) {
      int ci = i * 256 + t;          // 512 chunks of 16B per 8KB tile
      int row = ci >> 2;             // 4 chunks per 64B row
      int ce = (ci & 3) * 8;
      gload_lds16(A + (size_t)(m0 + row) * 1024 + kt * 32 + ce,
                  sA + buf * 4096 + (i * 256 + w * 64) * 8);
      gload_lds16(B + (size_t)(n0 + row) * 1024 + kt * 32 + ce,
                  sB + buf * 4096 + (i * 256 + w * 64) * 8);
    }
  };

  stage(0, 0);
  for (int kt = 0; kt < 32; ++kt) {
    const int cur = kt & 1;
    if (kt < 31) {
      stage(kt + 1, cur ^ 1);                       // 4 vmem insts in flight
      asm volatile("s_waitcnt vmcnt(4)" ::: "memory");  // wait cur tile only
    } else {
      asm volatile("s_waitcnt vmcnt(0)" ::: "memory");
    }
    __builtin_amdgcn_s_barrier();
    __builtin_amdgcn_sched_barrier(0);
    const ushort* pA = sA + cur * 4096;
    const ushort* pB = sB + cur * 4096;
    s16x8 af[4], bfr[4];
#pragma unroll
    for (int mi = 0; mi < 4; ++mi)
      af[mi] = *(const s16x8*)(pA + (wm + mi * 16 + lrow) * 32 + lk);
#pragma unroll
    for (int ni = 0; ni < 4; ++ni)
      bfr[ni] = *(const s16x8*)(pB + (wn + ni * 16 + lrow) * 32 + lk);
    __builtin_amdgcn_s_setprio(1);
#pragma unroll
    for (int mi = 0; mi < 4; ++mi)
#pragma unroll
      for (int ni = 0; ni < 4; ++ni)
        acc[mi][ni] = __builtin_amdgcn_mfma_f32_16x16x32_bf16(af[mi], bfr[ni], acc[mi][ni], 0, 0, 0);
    __builtin_amdgcn_s_setprio(0);
    asm volatile("s_waitcnt lgkmcnt(0)" ::: "memory");
    __builtin_amdgcn_s_barrier();
  }
}

// epilogue for bf16 head-major / transposed-V outputs
__device__ __forceinline__ void epi_heads(f32x4 (&acc)[4][4], ushort* D, float scale, bool vtrans) {
  const int lane = threadIdx.x & 63, w = threadIdx.x >> 6;
  const int m0 = blockIdx.x * 128, n0 = blockIdx.y * 128;
  const int wm = (w >> 1) * 64, wn = (w & 1) * 64;
#pragma unroll
  for (int mi = 0; mi < 4; ++mi)
#pragma unroll
    for (int ni = 0; ni < 4; ++ni)
#pragma unroll
      for (int r = 0; r < 4; ++r) {
        int m = m0 + wm + mi * 16 + (lane >> 4) * 4 + r;
        int n = n0 + wn + ni * 16 + (lane & 15);
        ushort bv = f2bf(acc[mi][ni][r] * scale);
        int b = m >> 11, s = m & 2047, h = n >> 6, d = n & 63;
        if (vtrans)
          D[((size_t)((b * 16 + h) * 64 + d)) * 2048 + s] = bv;   // V^T [bh][d][s]
        else
          D[((size_t)((b * 16 + h) * 2048 + s)) * 64 + d] = bv;   // Qh/Kh [bh][s][d]
      }
}

__global__ __launch_bounds__(256) void gemm_qkv(const ushort* __restrict__ qb,
                                                const ushort* __restrict__ kb,
                                                const ushort* __restrict__ vb,
                                                const ushort* __restrict__ wqb,
                                                const ushort* __restrict__ wkb,
                                                const ushort* __restrict__ wvb,
                                                ushort* __restrict__ Qh,
                                                ushort* __restrict__ Kh,
                                                ushort* __restrict__ Vt) {
  __shared__ __align__(16) ushort sA[2 * 128 * 32];
  __shared__ __align__(16) ushort sB[2 * 128 * 32];
  const int z = blockIdx.z;
  const ushort* A = (z == 0) ? qb : (z == 1) ? kb : vb;
  const ushort* B = (z == 0) ? wqb : (z == 1) ? wkb : wvb;
  f32x4 acc[4][4] = {};
  gemm_core(A, B, sA, sB, acc);
  ushort* D = (z == 0) ? Qh : (z == 1) ? Kh : Vt;
  epi_heads(acc, D, (z == 0) ? 0.125f : 1.0f, z == 2);
}

__global__ __launch_bounds__(256) void gemm_out(const ushort* __restrict__ A,
                                                const ushort* __restrict__ B,
                                                float* __restrict__ D) {
  __shared__ __align__(16) ushort sA[2 * 128 * 32];
  __shared__ __align__(16) ushort sB[2 * 128 * 32];
  f32x4 acc[4][4] = {};
  gemm_core(A, B, sA, sB, acc);
  const int lane = threadIdx.x & 63, w = threadIdx.x >> 6;
  const int m0 = blockIdx.x * 128, n0 = blockIdx.y * 128;
  const int wm = (w >> 1) * 64, wn = (w & 1) * 64;
#pragma unroll
  for (int mi = 0; mi < 4; ++mi)
#pragma unroll
    for (int ni = 0; ni < 4; ++ni)
#pragma unroll
      for (int r = 0; r < 4; ++r) {
        int m = m0 + wm + mi * 16 + (lane >> 4) * 4 + r;
        int n = n0 + wn + ni * 16 + (lane & 15);
        D[(size_t)m * 1024 + n] = acc[mi][ni][r];
      }
}

// ---------------- causal flash attention, paired q-tiles ----------------
// grid (16, B*H). Block p handles q-tiles {p, 31-p} (64 rows each) -> uniform 33 units/block.
// 4 waves; each wave owns 16 q-rows of each set. KV tiles of 64, double-buffered,
// counted vmcnt, raw barriers. K/V frag LDS reads shared across both q-sets.
__device__ __forceinline__ void softmax_p(f32x4 (&sc)[4], float* mr, float* lrp,
                                          f32x4* o, ushort* Pw, int lcol, int lhi) {
#pragma unroll
  for (int r = 0; r < 4; ++r) {
    float tm = fmaxf(fmaxf(sc[0][r], sc[1][r]), fmaxf(sc[2][r], sc[3][r]));
    tm = fmaxf(tm, __shfl_xor(tm, 1));
    tm = fmaxf(tm, __shfl_xor(tm, 2));
    tm = fmaxf(tm, __shfl_xor(tm, 4));
    tm = fmaxf(tm, __shfl_xor(tm, 8));
    float mn = fmaxf(mr[r], tm);
    float alpha = __expf(mr[r] - mn);
    float rs = 0.f;
#pragma unroll
    for (int ktt = 0; ktt < 4; ++ktt) {
      float p = __expf(sc[ktt][r] - mn);
      sc[ktt][r] = p;
      rs += p;
    }
    mr[r] = mn;
    lrp[r] = lrp[r] * alpha + rs;   // lane-local partial sum; butterfly at epilogue
    o[0][r] *= alpha; o[1][r] *= alpha; o[2][r] *= alpha; o[3][r] *= alpha;
#pragma unroll
    for (int ktt = 0; ktt < 4; ++ktt)
      Pw[(lhi * 4 + r) * 72 + ktt * 16 + lcol] = f2bf(sc[ktt][r]);
  }
}

__global__ __launch_bounds__(256) void attn_fwd(const ushort* __restrict__ Qh,
                                                const ushort* __restrict__ Kh,
                                                const ushort* __restrict__ Vt,
                                                ushort* __restrict__ Z) {
  __shared__ __align__(16) ushort sK[2][64 * 64];      // [k][d], chunk-XOR swizzled
  __shared__ __align__(16) ushort sV[2][64 * 64];      // [d][k], chunk-XOR swizzled
  __shared__ __align__(16) ushort sP[4][2][16 * 72];   // per-wave, per-set P
  const int t = threadIdx.x, w = t >> 6, lane = t & 63;
  const int lcol = lane & 15, lhi = lane >> 4;
  const int p = blockIdx.x, bh = blockIdx.y;
  const int qlo = p, qhi = 31 - p;
  const ushort* Qb = Qh + (size_t)bh * SQL * DKH;
  const ushort* Kb = Kh + (size_t)bh * SQL * DKH;
  const ushort* Vb = Vt + (size_t)bh * DKH * SQL;

  // Q A-fragments for both sets, resident in registers
  s16x8 qf[2][2];
#pragma unroll
  for (int s = 0; s < 2; ++s) {
    int qr0 = (s == 0 ? qlo : qhi) * 64 + w * 16;
    const ushort* qp = Qb + (size_t)(qr0 + lcol) * DKH + lhi * 8;
    qf[s][0] = *(const s16x8*)qp;
    qf[s][1] = *(const s16x8*)(qp + 32);
  }
  float mr[2][4], lrp[2][4];
  f32x4 o[2][4] = {};
#pragma unroll
  for (int s = 0; s < 2; ++s)
#pragma unroll
    for (int r = 0; r < 4; ++r) { mr[s][r] = -1e30f; lrp[s][r] = 0.f; }
  ushort* Pw0 = &sP[w][0][0];
  ushort* Pw1 = &sP[w][1][0];

  auto stage = [&](int kb, int buf) {
#pragma unroll
    for (int i = 0; i < 2; ++i) {
      int ci = i * 256 + t;
      int row = ci >> 3, cc = ci & 7;
      int scz = cc ^ (row & 7);      // pre-swizzled source -> linear LDS dest
      gload_lds16(Kb + (size_t)(kb * 64 + row) * DKH + scz * 8, &sK[buf][(i * 256 + w * 64) * 8]);
      gload_lds16(Vb + (size_t)row * SQL + kb * 64 + scz * 8, &sV[buf][(i * 256 + w * 64) * 8]);
    }
  };

  const int nkb = qhi + 1;
  stage(0, 0);
  for (int kb = 0; kb < nkb; ++kb) {
    const int cur = kb & 1;
    if (kb + 1 < nkb) {
      stage(kb + 1, cur ^ 1);                        // 4 vmem insts
      asm volatile("s_waitcnt vmcnt(4)" ::: "memory");
    } else {
      asm volatile("s_waitcnt vmcnt(0)" ::: "memory");
    }
    __builtin_amdgcn_s_barrier();
    __builtin_amdgcn_sched_barrier(0);
    const ushort* pK = &sK[cur][0];
    const ushort* pV = &sV[cur][0];
    const bool act0 = (kb <= qlo);

    // QK^T for both sets, k-fragments loaded once
    f32x4 s0[4], s1[4];
    __builtin_amdgcn_s_setprio(1);
#pragma unroll
    for (int ktt = 0; ktt < 4; ++ktt) {
      int row = ktt * 16 + lcol;
      int c0 = lhi ^ (row & 7);
      int c1 = (lhi + 4) ^ (row & 7);
      s16x8 k0 = *(const s16x8*)(pK + row * 64 + c0 * 8);
      s16x8 k1 = *(const s16x8*)(pK + row * 64 + c1 * 8);
      f32x4 a = {};
      a = __builtin_amdgcn_mfma_f32_16x16x32_bf16(qf[1][0], k0, a, 0, 0, 0);
      a = __builtin_amdgcn_mfma_f32_16x16x32_bf16(qf[1][1], k1, a, 0, 0, 0);
      s1[ktt] = a;
      if (act0) {
        f32x4 b2 = {};
        b2 = __builtin_amdgcn_mfma_f32_16x16x32_bf16(qf[0][0], k0, b2, 0, 0, 0);
        b2 = __builtin_amdgcn_mfma_f32_16x16x32_bf16(qf[0][1], k1, b2, 0, 0, 0);
        s0[ktt] = b2;
      }
    }
    __builtin_amdgcn_s_setprio(0);

    // causal masks (diagonal tiles only)
    if (kb == qhi) {
#pragma unroll
      for (int ktt = 0; ktt < 4; ++ktt) {
        int kloc = ktt * 16 + lcol;
#pragma unroll
        for (int r = 0; r < 4; ++r)
          if (kloc > w * 16 + lhi * 4 + r) s1[ktt][r] = -1e30f;
      }
    }
    if (act0 && kb == qlo) {
#pragma unroll
      for (int ktt = 0; ktt < 4; ++ktt) {
        int kloc = ktt * 16 + lcol;
#pragma unroll
        for (int r = 0; r < 4; ++r)
          if (kloc > w * 16 + lhi * 4 + r) s0[ktt][r] = -1e30f;
      }
    }

    softmax_p(s1, mr[1], lrp[1], o[1], Pw1, lcol, lhi);
    if (act0) softmax_p(s0, mr[0], lrp[0], o[0], Pw0, lcol, lhi);

    // PV for both sets, v-fragments loaded once
    __builtin_amdgcn_s_setprio(1);
#pragma unroll
    for (int kc = 0; kc < 2; ++kc) {
      s16x8 pf1 = *(const s16x8*)(Pw1 + lcol * 72 + kc * 32 + lhi * 8);
      s16x8 pf0 = pf1;
      if (act0) pf0 = *(const s16x8*)(Pw0 + lcol * 72 + kc * 32 + lhi * 8);
#pragma unroll
      for (int dt = 0; dt < 4; ++dt) {
        int row = dt * 16 + lcol;
        int cc = (lhi + 4 * kc) ^ (row & 7);
        s16x8 vf = *(const s16x8*)(pV + row * 64 + cc * 8);
        o[1][dt] = __builtin_amdgcn_mfma_f32_16x16x32_bf16(pf1, vf, o[1][dt], 0, 0, 0);
        if (act0) o[0][dt] = __builtin_amdgcn_mfma_f32_16x16x32_bf16(pf0, vf, o[0][dt], 0, 0, 0);
      }
    }
    __builtin_amdgcn_s_setprio(0);
    asm volatile("s_waitcnt lgkmcnt(0)" ::: "memory");
    __builtin_amdgcn_s_barrier();
  }

  // epilogue: butterfly-sum denominators, O /= l, write Z[b][s][h*64+d]
  const int b = bh >> 4, h = bh & 15;
#pragma unroll
  for (int s = 0; s < 2; ++s) {
    int qbase = (s == 0 ? qlo : qhi) * 64 + w * 16;
#pragma unroll
    for (int r = 0; r < 4; ++r) {
      float sum = lrp[s][r];
      sum += __shfl_xor(sum, 1);
      sum += __shfl_xor(sum, 2);
      sum += __shfl_xor(sum, 4);
      sum += __shfl_xor(sum, 8);
      float inv = 1.0f / sum;
      int q = qbase + lhi * 4 + r;
      size_t base = ((size_t)(b * SQL + q)) * DMODEL + h * DKH + lcol;
#pragma unroll
      for (int dt = 0; dt < 4; ++dt)
        Z[base + dt * 16] = f2bf(o[s][dt][r] * inv);
    }
  }
}

// ---------------- launch ----------------
extern "C" void kernel_launch(void* const* d_in, const int* in_sizes, int n_in,
                              void* d_out, int out_size, void* d_ws, size_t ws_size,
                              hipStream_t stream) {
  const float* q = (const float*)d_in[0];
  const float* k = (const float*)d_in[1];
  const float* v = (const float*)d_in[2];
  // d_in[3] = causal mask (bool) -- derived analytically, ignored
  const float* wq = (const float*)d_in[4];
  const float* wk = (const float*)d_in[5];
  const float* wv = (const float*)d_in[6];
  const float* wo = (const float*)d_in[7];

  const size_t NBIG = (size_t)BSZ * SQL * DMODEL;   // 4194304
  const size_t NW = (size_t)DMODEL * DMODEL;        // 1048576
  ushort* qb = (ushort*)d_ws;
  ushort* kb = qb + NBIG;
  ushort* vb = kb + NBIG;
  ushort* wqb = vb + NBIG;
  ushort* wkb = wqb + NW;
  ushort* wvb = wkb + NW;
  ushort* wob = wvb + NW;
  ushort* Qh = wob + NW;
  ushort* Kh = Qh + NBIG;
  ushort* Vt = Kh + NBIG;
  ushort* Z  = Vt + NBIG;   // total 64 MiB of d_ws

  cvt3<<<dim3((unsigned)(NBIG / 1024), 3), 256, 0, stream>>>(q, k, v, qb, kb, vb);
  cvt4<<<dim3((unsigned)(NW / 1024), 4), 256, 0, stream>>>(wq, wk, wv, wo, wqb, wkb, wvb, wob);
  gemm_qkv<<<dim3(32, 8, 3), 256, 0, stream>>>(qb, kb, vb, wqb, wkb, wvb, Qh, Kh, Vt);
  attn_fwd<<<dim3(16, BSZ * NHEAD), 256, 0, stream>>>(Qh, Kh, Vt, Z);
  gemm_out<<<dim3(32, 8), 256, 0, stream>>>(Z, wob, (float*)d_out);
}

// Round 3
// 132.001 us; speedup vs baseline: 1.8542x; 1.1627x over previous
//
#include <hip/hip_runtime.h>
#include <hip/hip_bf16.h>
#include <stdint.h>

typedef short s16x8 __attribute__((ext_vector_type(8)));
typedef float f32x4 __attribute__((ext_vector_type(4)));

#define BSZ 2
#define SQL 2048
#define DMODEL 1024
#define NHEAD 16
#define DKH 64

#if __has_builtin(__builtin_amdgcn_exp2f)
#define EXP2(x) __builtin_amdgcn_exp2f(x)
#else
#define EXP2(x) exp2f(x)
#endif

// fp32 -> bf16 round-to-nearest-even
__device__ __forceinline__ ushort f2bf(float f) {
  uint32_t u = __float_as_uint(f);
  u += 0x7fffu + ((u >> 16) & 1u);
  return (ushort)(u >> 16);
}

// pack two f32 -> 2x bf16 in one u32 (lo -> low half)
__device__ __forceinline__ uint32_t cvtpk_bf16(float lo, float hi) {
  uint32_t r;
  asm("v_cvt_pk_bf16_f32 %0, %1, %2" : "=v"(r) : "v"(lo), "v"(hi));
  return r;
}

// max-reduce across the 16-lane DPP row via row_ror 1,2,4,8 (VALU, no DS pipe)
__device__ __forceinline__ float rowmax16(float x) {
  x = fmaxf(x, __int_as_float(__builtin_amdgcn_update_dpp(0, __float_as_int(x), 0x121, 0xf, 0xf, true)));
  x = fmaxf(x, __int_as_float(__builtin_amdgcn_update_dpp(0, __float_as_int(x), 0x122, 0xf, 0xf, true)));
  x = fmaxf(x, __int_as_float(__builtin_amdgcn_update_dpp(0, __float_as_int(x), 0x124, 0xf, 0xf, true)));
  x = fmaxf(x, __int_as_float(__builtin_amdgcn_update_dpp(0, __float_as_int(x), 0x128, 0xf, 0xf, true)));
  return x;
}

// async global->LDS, 16B per lane. LDS dest is wave-uniform base + lane*16.
__device__ __forceinline__ void gload_lds16(const ushort* g, ushort* l) {
  __builtin_amdgcn_global_load_lds((const __attribute__((address_space(1))) void*)g,
                                   (__attribute__((address_space(3))) void*)l,
                                   16, 0, 0);
}

// ---------------- fp32 -> bf16 conversion (single launch) ----------------
// blocks 0..12287: q,k,v (4096 each); 12288..16383: wq,wk,wv,wo (1024 each)
__global__ void cvt_all(const float* __restrict__ q, const float* __restrict__ k,
                        const float* __restrict__ v, const float* __restrict__ wq,
                        const float* __restrict__ wk, const float* __restrict__ wv,
                        const float* __restrict__ wo, ushort* __restrict__ dq,
                        ushort* __restrict__ dk, ushort* __restrict__ dv,
                        ushort* __restrict__ dwq, ushort* __restrict__ dwk,
                        ushort* __restrict__ dwv, ushort* __restrict__ dwo) {
  int b = blockIdx.x;
  const float* s; ushort* d; int off;
  if (b < 4096)       { s = q;  d = dq;  off = b; }
  else if (b < 8192)  { s = k;  d = dk;  off = b - 4096; }
  else if (b < 12288) { s = v;  d = dv;  off = b - 8192; }
  else if (b < 13312) { s = wq; d = dwq; off = b - 12288; }
  else if (b < 14336) { s = wk; d = dwk; off = b - 13312; }
  else if (b < 15360) { s = wv; d = dwv; off = b - 14336; }
  else                { s = wo; d = dwo; off = b - 15360; }
  int i = (off * 256 + threadIdx.x) * 4;
  float4 x = *(const float4*)(s + i);
  ushort4 o;
  o.x = f2bf(x.x); o.y = f2bf(x.y); o.z = f2bf(x.z); o.w = f2bf(x.w);
  *(ushort4*)(d + i) = o;
}

// ---------------- GEMM core: C[M,N] = A[M,K] * B[N,K]^T, bf16 in, fp32 acc -------------
// M=4096 N=1024 K=1024. 128x128 tile, BK=32, 4 waves (2x2 of 64x64), 16x16x32 MFMA.
__device__ __forceinline__ void gemm_core(const ushort* __restrict__ A,
                                          const ushort* __restrict__ B,
                                          ushort* sA, ushort* sB, f32x4 (&acc)[4][4]) {
  const int t = threadIdx.x, w = t >> 6, lane = t & 63;
  const int lrow = lane & 15, lk = (lane >> 4) * 8;
  const int m0 = blockIdx.x * 128, n0 = blockIdx.y * 128;
  const int wm = (w >> 1) * 64, wn = (w & 1) * 64;

  auto stage = [&](int kt, int buf) {
#pragma unroll
    for (int i = 0; i < 2; ++i) {
      int ci = i * 256 + t;
      int row = ci >> 2;
      int ce = (ci & 3) * 8;
      gload_lds16(A + (size_t)(m0 + row) * 1024 + kt * 32 + ce,
                  sA + buf * 4096 + (i * 256 + w * 64) * 8);
      gload_lds16(B + (size_t)(n0 + row) * 1024 + kt * 32 + ce,
                  sB + buf * 4096 + (i * 256 + w * 64) * 8);
    }
  };

  stage(0, 0);
  for (int kt = 0; kt < 32; ++kt) {
    const int cur = kt & 1;
    if (kt < 31) {
      stage(kt + 1, cur ^ 1);
      asm volatile("s_waitcnt vmcnt(4)" ::: "memory");
    } else {
      asm volatile("s_waitcnt vmcnt(0)" ::: "memory");
    }
    __builtin_amdgcn_s_barrier();
    __builtin_amdgcn_sched_barrier(0);
    const ushort* pA = sA + cur * 4096;
    const ushort* pB = sB + cur * 4096;
    s16x8 af[4], bfr[4];
#pragma unroll
    for (int mi = 0; mi < 4; ++mi)
      af[mi] = *(const s16x8*)(pA + (wm + mi * 16 + lrow) * 32 + lk);
#pragma unroll
    for (int ni = 0; ni < 4; ++ni)
      bfr[ni] = *(const s16x8*)(pB + (wn + ni * 16 + lrow) * 32 + lk);
    __builtin_amdgcn_s_setprio(1);
#pragma unroll
    for (int mi = 0; mi < 4; ++mi)
#pragma unroll
      for (int ni = 0; ni < 4; ++ni)
        acc[mi][ni] = __builtin_amdgcn_mfma_f32_16x16x32_bf16(af[mi], bfr[ni], acc[mi][ni], 0, 0, 0);
    __builtin_amdgcn_s_setprio(0);
    asm volatile("s_waitcnt lgkmcnt(0)" ::: "memory");
    __builtin_amdgcn_s_barrier();
  }
}

__device__ __forceinline__ void epi_heads(f32x4 (&acc)[4][4], ushort* D, float scale, bool vtrans) {
  const int lane = threadIdx.x & 63, w = threadIdx.x >> 6;
  const int m0 = blockIdx.x * 128, n0 = blockIdx.y * 128;
  const int wm = (w >> 1) * 64, wn = (w & 1) * 64;
#pragma unroll
  for (int mi = 0; mi < 4; ++mi)
#pragma unroll
    for (int ni = 0; ni < 4; ++ni)
#pragma unroll
      for (int r = 0; r < 4; ++r) {
        int m = m0 + wm + mi * 16 + (lane >> 4) * 4 + r;
        int n = n0 + wn + ni * 16 + (lane & 15);
        ushort bv = f2bf(acc[mi][ni][r] * scale);
        int b = m >> 11, s = m & 2047, h = n >> 6, d = n & 63;
        if (vtrans)
          D[((size_t)((b * 16 + h) * 64 + d)) * 2048 + s] = bv;   // V^T [bh][d][s]
        else
          D[((size_t)((b * 16 + h) * 2048 + s)) * 64 + d] = bv;   // Qh/Kh [bh][s][d]
      }
}

__global__ __launch_bounds__(256) void gemm_qkv(const ushort* __restrict__ qb,
                                                const ushort* __restrict__ kb,
                                                const ushort* __restrict__ vb,
                                                const ushort* __restrict__ wqb,
                                                const ushort* __restrict__ wkb,
                                                const ushort* __restrict__ wvb,
                                                ushort* __restrict__ Qh,
                                                ushort* __restrict__ Kh,
                                                ushort* __restrict__ Vt) {
  __shared__ __align__(16) ushort sA[2 * 128 * 32];
  __shared__ __align__(16) ushort sB[2 * 128 * 32];
  const int z = blockIdx.z;
  const ushort* A = (z == 0) ? qb : (z == 1) ? kb : vb;
  const ushort* B = (z == 0) ? wqb : (z == 1) ? wkb : wvb;
  f32x4 acc[4][4] = {};
  gemm_core(A, B, sA, sB, acc);
  ushort* D = (z == 0) ? Qh : (z == 1) ? Kh : Vt;
  // Q pre-scaled by 1/sqrt(dk) * log2(e) so softmax runs in exp2 domain
  epi_heads(acc, D, (z == 0) ? 0.18033688f : 1.0f, z == 2);
}

__global__ __launch_bounds__(256) void gemm_out(const ushort* __restrict__ A,
                                                const ushort* __restrict__ B,
                                                float* __restrict__ D) {
  __shared__ __align__(16) ushort sA[2 * 128 * 32];
  __shared__ __align__(16) ushort sB[2 * 128 * 32];
  f32x4 acc[4][4] = {};
  gemm_core(A, B, sA, sB, acc);
  const int lane = threadIdx.x & 63, w = threadIdx.x >> 6;
  const int m0 = blockIdx.x * 128, n0 = blockIdx.y * 128;
  const int wm = (w >> 1) * 64, wn = (w & 1) * 64;
#pragma unroll
  for (int mi = 0; mi < 4; ++mi)
#pragma unroll
    for (int ni = 0; ni < 4; ++ni)
#pragma unroll
      for (int r = 0; r < 4; ++r) {
        int m = m0 + wm + mi * 16 + (lane >> 4) * 4 + r;
        int n = n0 + wn + ni * 16 + (lane & 15);
        D[(size_t)m * 1024 + n] = acc[mi][ni][r];
      }
}

// ---------------- causal flash attention, paired q-tiles, 8 waves ----------------
// grid (16, B*H), 512 threads. Waves 0-3 own q-tile p, waves 4-7 own q-tile 31-p.
// Each wave: 16 q-rows. KV tiles of 64, double-buffered, counted vmcnt.
// Scores arrive pre-scaled into log2 domain (Q scale folded); softmax uses exp2.
__global__ __launch_bounds__(512) void attn_fwd(const ushort* __restrict__ Qh,
                                                const ushort* __restrict__ Kh,
                                                const ushort* __restrict__ Vt,
                                                ushort* __restrict__ Z) {
  __shared__ __align__(16) ushort sK[2][64 * 64];   // [k][d], chunk-XOR swizzled
  __shared__ __align__(16) ushort sV[2][64 * 64];   // [d][k], chunk-XOR swizzled
  __shared__ __align__(16) ushort sP[8][16 * 72];   // per-wave P
  const int t = threadIdx.x, w = t >> 6, lane = t & 63;
  const int lcol = lane & 15, lhi = lane >> 4;
  const int p = blockIdx.x, bh = blockIdx.y;
  const int qlo = p, qhi = 31 - p;
  const int setid = w >> 2;
  const int qtile = setid ? qhi : qlo;
  const int qr0 = qtile * 64 + (w & 3) * 16;
  const ushort* Qb = Qh + (size_t)bh * SQL * DKH;
  const ushort* Kb = Kh + (size_t)bh * SQL * DKH;
  const ushort* Vb = Vt + (size_t)bh * DKH * SQL;

  s16x8 qf0, qf1;
  {
    const ushort* qp = Qb + (size_t)(qr0 + lcol) * DKH + lhi * 8;
    qf0 = *(const s16x8*)qp;
    qf1 = *(const s16x8*)(qp + 32);
  }
  float mr[4], lrp[4];
  f32x4 o[4] = {};
#pragma unroll
  for (int r = 0; r < 4; ++r) { mr[r] = -1e30f; lrp[r] = 0.f; }
  ushort* Pw = &sP[w][0];

  auto stage = [&](int kb, int buf) {
    int row = t >> 3, cc = t & 7;
    int scz = cc ^ (row & 7);        // pre-swizzled source -> linear LDS dest
    gload_lds16(Kb + (size_t)(kb * 64 + row) * DKH + scz * 8, &sK[buf][w * 512]);
    gload_lds16(Vb + (size_t)row * SQL + kb * 64 + scz * 8, &sV[buf][w * 512]);
  };

  const int nkb = qhi + 1;
  stage(0, 0);
  for (int kb = 0; kb < nkb; ++kb) {
    const int cur = kb & 1;
    if (kb + 1 < nkb) {
      stage(kb + 1, cur ^ 1);                        // 2 vmem in flight
      asm volatile("s_waitcnt vmcnt(2)" ::: "memory");
    } else {
      asm volatile("s_waitcnt vmcnt(0)" ::: "memory");
    }
    __builtin_amdgcn_s_barrier();
    __builtin_amdgcn_sched_barrier(0);
    const bool act = setid || (kb <= qlo);
    if (act) {
      const ushort* pK = &sK[cur][0];
      const ushort* pV = &sV[cur][0];
      // QK^T
      f32x4 sc4[4];
      __builtin_amdgcn_s_setprio(1);
#pragma unroll
      for (int ktt = 0; ktt < 4; ++ktt) {
        int row = ktt * 16 + lcol;
        int c0 = lhi ^ (row & 7);
        int c1 = (lhi + 4) ^ (row & 7);
        s16x8 k0 = *(const s16x8*)(pK + row * 64 + c0 * 8);
        s16x8 k1 = *(const s16x8*)(pK + row * 64 + c1 * 8);
        f32x4 a = {};
        a = __builtin_amdgcn_mfma_f32_16x16x32_bf16(qf0, k0, a, 0, 0, 0);
        a = __builtin_amdgcn_mfma_f32_16x16x32_bf16(qf1, k1, a, 0, 0, 0);
        sc4[ktt] = a;
      }
      __builtin_amdgcn_s_setprio(0);
      // causal mask on the diagonal tile
      if (kb == qtile) {
#pragma unroll
        for (int ktt = 0; ktt < 4; ++ktt) {
          int kloc = ktt * 16 + lcol;
#pragma unroll
          for (int r = 0; r < 4; ++r)
            if (kloc > (w & 3) * 16 + lhi * 4 + r) sc4[ktt][r] = -1e30f;
        }
      }
      // online softmax (log2 domain), defer-max rescale
      float tm4[4];
#pragma unroll
      for (int r = 0; r < 4; ++r) {
        float tm = fmaxf(fmaxf(sc4[0][r], sc4[1][r]), fmaxf(sc4[2][r], sc4[3][r]));
        tm4[r] = rowmax16(tm);
      }
      bool grow = (tm4[0] > mr[0] + 8.f) || (tm4[1] > mr[1] + 8.f) ||
                  (tm4[2] > mr[2] + 8.f) || (tm4[3] > mr[3] + 8.f);
      if (__any((int)grow)) {
#pragma unroll
        for (int r = 0; r < 4; ++r) {
          float mn = fmaxf(mr[r], tm4[r]);
          float al = EXP2(mr[r] - mn);
          lrp[r] *= al;
          o[0][r] *= al; o[1][r] *= al; o[2][r] *= al; o[3][r] *= al;
          mr[r] = mn;
        }
      }
#pragma unroll
      for (int r = 0; r < 4; ++r) {
        float p0 = EXP2(sc4[0][r] - mr[r]);
        float p1 = EXP2(sc4[1][r] - mr[r]);
        float p2 = EXP2(sc4[2][r] - mr[r]);
        float p3 = EXP2(sc4[3][r] - mr[r]);
        lrp[r] += (p0 + p1) + (p2 + p3);
        uint32_t w01 = cvtpk_bf16(p0, p1);
        uint32_t w23 = cvtpk_bf16(p2, p3);
        ushort* pr = Pw + (lhi * 4 + r) * 72 + lcol;
        pr[0]  = (ushort)(w01 & 0xffffu);
        pr[16] = (ushort)(w01 >> 16);
        pr[32] = (ushort)(w23 & 0xffffu);
        pr[48] = (ushort)(w23 >> 16);
      }
      // PV
      __builtin_amdgcn_s_setprio(1);
#pragma unroll
      for (int kc = 0; kc < 2; ++kc) {
        s16x8 pf = *(const s16x8*)(Pw + lcol * 72 + kc * 32 + lhi * 8);
#pragma unroll
        for (int dt = 0; dt < 4; ++dt) {
          int row = dt * 16 + lcol;
          int cc = (lhi + 4 * kc) ^ (row & 7);
          s16x8 vf = *(const s16x8*)(pV + row * 64 + cc * 8);
          o[dt] = __builtin_amdgcn_mfma_f32_16x16x32_bf16(pf, vf, o[dt], 0, 0, 0);
        }
      }
      __builtin_amdgcn_s_setprio(0);
    }
    asm volatile("s_waitcnt lgkmcnt(0)" ::: "memory");
    __builtin_amdgcn_s_barrier();
  }

  // epilogue: reduce denominators over the 16 k-lanes, normalize, write Z
  const int b = bh >> 4, h = bh & 15;
#pragma unroll
  for (int r = 0; r < 4; ++r) {
    float sum = lrp[r];
    sum += __shfl_xor(sum, 1);
    sum += __shfl_xor(sum, 2);
    sum += __shfl_xor(sum, 4);
    sum += __shfl_xor(sum, 8);
    float inv = 1.0f / sum;
    int q = qr0 + lhi * 4 + r;
    size_t base = ((size_t)(b * SQL + q)) * DMODEL + h * DKH + lcol;
#pragma unroll
    for (int dt = 0; dt < 4; ++dt)
      Z[base + dt * 16] = f2bf(o[dt][r] * inv);
  }
}

// ---------------- launch ----------------
extern "C" void kernel_launch(void* const* d_in, const int* in_sizes, int n_in,
                              void* d_out, int out_size, void* d_ws, size_t ws_size,
                              hipStream_t stream) {
  const float* q = (const float*)d_in[0];
  const float* k = (const float*)d_in[1];
  const float* v = (const float*)d_in[2];
  // d_in[3] = causal mask (bool) -- derived analytically, ignored
  const float* wq = (const float*)d_in[4];
  const float* wk = (const float*)d_in[5];
  const float* wv = (const float*)d_in[6];
  const float* wo = (const float*)d_in[7];

  const size_t NBIG = (size_t)BSZ * SQL * DMODEL;   // 4194304
  const size_t NW = (size_t)DMODEL * DMODEL;        // 1048576
  ushort* qb = (ushort*)d_ws;
  ushort* kb = qb + NBIG;
  ushort* vb = kb + NBIG;
  ushort* wqb = vb + NBIG;
  ushort* wkb = wqb + NW;
  ushort* wvb = wkb + NW;
  ushort* wob = wvb + NW;
  ushort* Qh = wob + NW;
  ushort* Kh = Qh + NBIG;
  ushort* Vt = Kh + NBIG;
  ushort* Z  = Vt + NBIG;   // total 64 MiB of d_ws

  cvt_all<<<dim3(16384), 256, 0, stream>>>(q, k, v, wq, wk, wv, wo,
                                           qb, kb, vb, wqb, wkb, wvb, wob);
  gemm_qkv<<<dim3(32, 8, 3), 256, 0, stream>>>(qb, kb, vb, wqb, wkb, wvb, Qh, Kh, Vt);
  attn_fwd<<<dim3(16, BSZ * NHEAD), 512, 0, stream>>>(Qh, Kh, Vt, Z);
  gemm_out<<<dim3(32, 8), 256, 0, stream>>>(Z, wob, (float*)d_out);
}